// Round 19
// baseline (974.663 us; speedup 1.0000x reference)
//
#include <hip/hip_runtime.h>
#include <math.h>

#define NS 512
#define NE 2048
#define NB 64
#define NT 512
#define SENT 0x7FC0DEADu  // NaN payload; real values are always finite

// out[c][r] = in[r][c]; rows, cols multiples of 32
__global__ __launch_bounds__(256) void transpose_k(const float* __restrict__ in,
                                                   float* __restrict__ out,
                                                   int rows, int cols) {
  __shared__ float tile[32][33];
  int c0 = blockIdx.x * 32;
  int r0 = blockIdx.y * 32;
  int tx = threadIdx.x;  // 0..31
  int ty = threadIdx.y;  // 0..7
#pragma unroll
  for (int k = 0; k < 32; k += 8) {
    tile[ty + k][tx] = in[(size_t)(r0 + ty + k) * cols + (c0 + tx)];
  }
  __syncthreads();
#pragma unroll
  for (int k = 0; k < 32; k += 8) {
    out[(size_t)(c0 + ty + k) * rows + (r0 + tx)] = tile[tx][ty + k];
  }
}

// Fill vpre with the sentinel each call (slots write-once per call; harness
// does not re-poison between replays).
__global__ __launch_bounds__(256) void fill_sentinel(float* __restrict__ vpre) {
  uint4 s = make_uint4(SENT, SENT, SENT, SENT);
  uint4* p = reinterpret_cast<uint4*>(vpre);
  const size_t n4 = (size_t)NB * NT * NS / 4;
  for (size_t i = (size_t)blockIdx.x * blockDim.x + threadIdx.x; i < n4;
       i += (size_t)gridDim.x * blockDim.x)
    p[i] = s;
}

// Forward: dataflow column-slice, max-only, sentinel exchange (R17/R18 core).
// R19 deltas: (1) calibrated s_sleep(6) before the FIRST gather attempt —
// members are phase-locked, so attempt #1 otherwise arrives at the IC before
// the remote publish lands and pays a full extra round trip (the ~0.3us/iter
// slop R18 measured); (2) distributed E — every wave duplicate-merges the
// partials (identical cheap LDS work) and wave o publishes its own 8 columns,
// removing the wave0-serialized merge+publish tail from the chain. vf is still
// written ONLY by wave0 (sole writer, consumed by wave0 next iter: no race).
__global__ __launch_bounds__(512) void viterbi_fwd(
    const int* __restrict__ obs,     // [NB][NT]
    const float* __restrict__ start, // [NS]
    const float* __restrict__ trans, // [NS][NS]
    const float* __restrict__ emT,   // [NE][NS]
    float* __restrict__ vpre)        // [NB][NT][NS] exchange + bt input
{
  const int g = blockIdx.x & 63;
  const int m = blockIdx.x >> 6;       // member 0..7
  const int tid = threadIdx.x;
  const int jl = tid & 63;
  const int oct = tid >> 6;            // wave 0..7
  const int j = m * 64 + jl;           // my output column
  const int p = (m + oct) & 7;         // i-block this wave covers
  const int i0 = p * 64;

  __shared__ __align__(16) float vf[NS];
  __shared__ float part_v[2][8][64];
  __shared__ int obs_s[NT];

  obs_s[tid] = obs[g * NT + tid];
  {
    int o0 = obs[g * NT];
    vf[tid] = start[tid] + emT[(size_t)o0 * NS + tid];
    if (m == 0) vpre[(size_t)g * NT * NS + tid] = start[tid];
  }
  __syncthreads();

  for (int t = 1; t < NT; ++t) {
    const int par = t & 1;
    float e_own = 0.f;
    if (oct == 0) e_own = emT[(size_t)obs_s[t] * NS + j];  // for vf only

    // ---- per-wave gather of exactly my slice (sentinel retry) ----
    if (t >= 2 && oct != 0) {
      float e_gat = emT[(size_t)obs_s[t - 1] * NS + i0 + jl];  // in flight early
      const float* ap = vpre + ((size_t)g * NT + (t - 1)) * NS + i0 + jl;
      __builtin_amdgcn_s_sleep(6);  // ~384cy: arrive just AFTER remote publish lands
      float ga = __hip_atomic_load(ap, __ATOMIC_RELAXED, __HIP_MEMORY_SCOPE_AGENT);
      while (__any(__float_as_uint(ga) == SENT)) {
        __builtin_amdgcn_s_sleep(1);
        ga = __hip_atomic_load(ap, __ATOMIC_RELAXED, __HIP_MEMORY_SCOPE_AGENT);
      }
      vf[i0 + jl] = ga + e_gat;  // consumed only by this wave
    }

    // ---- compute block p for column j: max only (1.5 VALU/score) ----
    float acc = -INFINITY;
    {
      const float* tp = trans + (size_t)i0 * NS + j;
      const float4* va = reinterpret_cast<const float4*>(vf + i0);
#pragma unroll
      for (int c = 0; c < 16; ++c) {
        float4 x = va[c];
        float s0 = x.x + tp[(size_t)(4 * c + 0) * NS];
        float s1 = x.y + tp[(size_t)(4 * c + 1) * NS];
        float s2 = x.z + tp[(size_t)(4 * c + 2) * NS];
        float s3 = x.w + tp[(size_t)(4 * c + 3) * NS];
        acc = fmaxf(acc, fmaxf(fmaxf(s0, s1), fmaxf(s2, s3)));
      }
    }
    part_v[par][oct][jl] = acc;
    __syncthreads();  // the ONE barrier: parts(t) ready

    // ---- distributed E: every wave merges; wave oct publishes cols [8oct,+8) ----
    float mv = part_v[par][0][jl];
#pragma unroll
    for (int o = 1; o < 8; ++o) mv = fmaxf(mv, part_v[par][o][jl]);
    if ((jl >> 3) == oct)
      __hip_atomic_store(vpre + ((size_t)g * NT + t) * NS + j, mv,
                         __ATOMIC_RELAXED, __HIP_MEMORY_SCOPE_AGENT);
    if (oct == 0) vf[j] = mv + e_own;  // sole vf writer; read by wave0 next iter
  }
}

// Backtrace, producer/consumer (R18) + R19 delta: mstar ships via a second
// __shfl from the matching lane's registers (it already holds vpre[t-1][i]),
// removing the dependent broadcast ds_read (~100cy) from the serial chain.
__global__ __launch_bounds__(512) void viterbi_bt(
    const int* __restrict__ obs,      // [NB][NT]
    const float* __restrict__ emT,    // [NE][NS]
    const float* __restrict__ transT, // [NS][NS], transT[j][i] = trans[i][j]
    const float* __restrict__ vpre,   // [NB][NT][NS]
    int* __restrict__ path)           // [NB][NT] int32
{
  const int b = blockIdx.x;
  const int tid = threadIdx.x;
  const int lane = tid & 63;
  const int oct = tid >> 6;

  __shared__ float vstage[2][32][NS];  // 128 KB, chunk k lives in buf k&1
  __shared__ int obs_s[NT];

  obs_s[tid] = obs[b * NT + tid];

  // stage chunk 15 (rows 480..511) into buf 1 — all 512 threads
  {
    const float4* src = reinterpret_cast<const float4*>(vpre + ((size_t)b * NT + 480) * NS);
    float4* dst = reinterpret_cast<float4*>(&vstage[1][0][0]);
    for (int i = tid; i < 32 * NS / 4; i += 512) dst[i] = src[i];
  }
  __syncthreads();

  int state = 0;
  float mstar = 0.f;
  float4 ep0, ep1;  // emission row t-1, wave0 only

  if (oct == 0) {
    // final argmax over v[511] = vstage[1][31] + e[511] (first-wins)
    const float4* vr = reinterpret_cast<const float4*>(&vstage[1][31][0]);
    const float4* er = reinterpret_cast<const float4*>(emT + (size_t)obs_s[NT - 1] * NS);
    float4 a0 = vr[2 * lane], a1 = vr[2 * lane + 1];
    float4 e0 = er[2 * lane], e1 = er[2 * lane + 1];
    float s0 = a0.x + e0.x, s1 = a0.y + e0.y, s2 = a0.z + e0.z, s3 = a0.w + e0.w;
    float s4 = a1.x + e1.x, s5 = a1.y + e1.y, s6 = a1.z + e1.z, s7 = a1.w + e1.w;
    float lm = fmaxf(fmaxf(fmaxf(s0, s1), fmaxf(s2, s3)),
                     fmaxf(fmaxf(s4, s5), fmaxf(s6, s7)));
    float M = lm;
#pragma unroll
    for (int off = 1; off < 64; off <<= 1) M = fmaxf(M, __shfl_xor(M, off));
    int k = 7;
    float sv = a1.w;
    if (s6 == M) { k = 6; sv = a1.z; }
    if (s5 == M) { k = 5; sv = a1.y; }
    if (s4 == M) { k = 4; sv = a1.x; }
    if (s3 == M) { k = 3; sv = a0.w; }
    if (s2 == M) { k = 2; sv = a0.z; }
    if (s1 == M) { k = 1; sv = a0.y; }
    if (s0 == M) { k = 0; sv = a0.x; }
    unsigned long long bal = __ballot(lm == M);
    int fl_ = __ffsll(bal) - 1;
    state = __shfl(8 * lane + k, fl_);
    mstar = __shfl(sv, fl_);  // = vpre[511][state]
    if (lane == 0) path[b * NT + (NT - 1)] = state;
    const float4* ep = reinterpret_cast<const float4*>(emT + (size_t)obs_s[NT - 2] * NS);
    ep0 = ep[2 * lane];
    ep1 = ep[2 * lane + 1];
  }

  for (int k = 15; k >= 0; --k) {
    if (oct != 0) {
      if (k > 0) {  // stage chunk k-1 into buf (k-1)&1
        const float4* src =
            reinterpret_cast<const float4*>(vpre + ((size_t)b * NT + (k - 1) * 32) * NS);
        float4* dst = reinterpret_cast<float4*>(&vstage[(k - 1) & 1][0][0]);
        for (int i = tid - 64; i < 32 * NS / 4; i += 448) dst[i] = src[i];
      }
      if (k == 15) {  // warm my transT slice (1/8 of 1MB) into this XCD's L2
        const uint4* w = reinterpret_cast<const uint4*>(transT) +
                         (size_t)((b >> 3) & 7) * (NS * NS / 4 / 8);
        for (int i = tid - 64; i < NS * NS / 4 / 8; i += 448) {
          uint4 x = w[i];
          asm volatile("" ::"v"(x.x), "v"(x.y), "v"(x.z), "v"(x.w));
        }
      }
    } else {
      const int hi = (k == 15) ? (NT - 1) : (32 * k + 32);
      const int lo = 32 * k + 1;
      const int buf = k & 1;
      for (int t = hi; t >= lo; --t) {
        // candidates row t-1 (LDS, state-independent) + emission regs
        const float4* cv = reinterpret_cast<const float4*>(&vstage[buf][(t - 1) & 31][0]);
        float4 vp0 = cv[2 * lane], vp1 = cv[2 * lane + 1];
        // dependent load: transT row for current state (L2-warm)
        const float4* tr = reinterpret_cast<const float4*>(transT + (size_t)state * NS);
        float4 t0 = tr[2 * lane], t1 = tr[2 * lane + 1];
        // prefetch next emission row (t-2), independent of state
        float4 ne0 = ep0, ne1 = ep1;
        if (t >= 2) {
          const float4* ep = reinterpret_cast<const float4*>(emT + (size_t)obs_s[t - 2] * NS);
          ne0 = ep[2 * lane];
          ne1 = ep[2 * lane + 1];
        }
        float c0 = vp0.x + ep0.x, c1 = vp0.y + ep0.y, c2 = vp0.z + ep0.z, c3 = vp0.w + ep0.w;
        float c4 = vp1.x + ep1.x, c5 = vp1.y + ep1.y, c6 = vp1.z + ep1.z, c7 = vp1.w + ep1.w;
        bool m0 = (c0 + t0.x) == mstar, m1 = (c1 + t0.y) == mstar;
        bool m2 = (c2 + t0.z) == mstar, m3 = (c3 + t0.w) == mstar;
        bool m4 = (c4 + t1.x) == mstar, m5 = (c5 + t1.y) == mstar;
        bool m6 = (c6 + t1.z) == mstar, m7 = (c7 + t1.w) == mstar;
        int kk = 7;
        float sv = vp1.w;
        if (m6) { kk = 6; sv = vp1.z; }
        if (m5) { kk = 5; sv = vp1.y; }
        if (m4) { kk = 4; sv = vp1.x; }
        if (m3) { kk = 3; sv = vp0.w; }
        if (m2) { kk = 2; sv = vp0.z; }
        if (m1) { kk = 1; sv = vp0.y; }
        if (m0) { kk = 0; sv = vp0.x; }
        unsigned long long bal = __ballot(m0 | m1 | m2 | m3 | m4 | m5 | m6 | m7);
        int fl_ = __ffsll(bal) - 1;
        state = __shfl(8 * lane + kk, fl_);
        mstar = __shfl(sv, fl_);  // = vpre[t-1][state], from the matching lane's regs
        if (lane == 0) path[b * NT + t - 1] = state;
        ep0 = ne0;
        ep1 = ne1;
      }
    }
    __syncthreads();  // chunk k-1 staged; wave0 done with chunk k
  }
}

extern "C" void kernel_launch(void* const* d_in, const int* in_sizes, int n_in,
                              void* d_out, int out_size, void* d_ws, size_t ws_size,
                              hipStream_t stream) {
  const int* obs = (const int*)d_in[0];       // [64][512]
  const float* start = (const float*)d_in[1]; // [512]
  const float* trans = (const float*)d_in[2]; // [512][512]
  const float* emis = (const float*)d_in[3];  // [512][2048]
  int* path = (int*)d_out;                    // [64][512] int32

  char* ws = (char*)d_ws;
  float* emT = (float*)ws;                           // [2048][512] = 4 MB
  float* transT = (float*)(ws + (4ull << 20));       // [512][512]  = 1 MB
  float* vpre = (float*)(ws + (5ull << 20));         // [64][512][512] = 64 MB

  fill_sentinel<<<1024, 256, 0, stream>>>(vpre);

  dim3 tb(32, 8);
  transpose_k<<<dim3(NE / 32, NS / 32), tb, 0, stream>>>(emis, emT, NS, NE);
  transpose_k<<<dim3(NS / 32, NS / 32), tb, 0, stream>>>(trans, transT, NS, NS);
  viterbi_fwd<<<512, 512, 0, stream>>>(obs, start, trans, emT, vpre);
  viterbi_bt<<<NB, 512, 0, stream>>>(obs, emT, transT, vpre, path);
}

// Round 20
// 901.635 us; speedup vs baseline: 1.0810x; 1.0810x over previous
//
#include <hip/hip_runtime.h>
#include <math.h>

#define NS 512
#define NE 2048
#define NB 64
#define NT 512
#define SENT 0x7FC0DEADu  // NaN payload; real values are always finite

// out[c][r] = in[r][c]; rows, cols multiples of 32
__global__ __launch_bounds__(256) void transpose_k(const float* __restrict__ in,
                                                   float* __restrict__ out,
                                                   int rows, int cols) {
  __shared__ float tile[32][33];
  int c0 = blockIdx.x * 32;
  int r0 = blockIdx.y * 32;
  int tx = threadIdx.x;  // 0..31
  int ty = threadIdx.y;  // 0..7
#pragma unroll
  for (int k = 0; k < 32; k += 8) {
    tile[ty + k][tx] = in[(size_t)(r0 + ty + k) * cols + (c0 + tx)];
  }
  __syncthreads();
#pragma unroll
  for (int k = 0; k < 32; k += 8) {
    out[(size_t)(c0 + ty + k) * rows + (r0 + tx)] = tile[tx][ty + k];
  }
}

// Fill vpre with the sentinel each call (slots write-once per call; harness
// does not re-poison between replays).
__global__ __launch_bounds__(256) void fill_sentinel(float* __restrict__ vpre) {
  uint4 s = make_uint4(SENT, SENT, SENT, SENT);
  uint4* p = reinterpret_cast<uint4*>(vpre);
  const size_t n4 = (size_t)NB * NT * NS / 4;
  for (size_t i = (size_t)blockIdx.x * blockDim.x + threadIdx.x; i < n4;
       i += (size_t)gridDim.x * blockDim.x)
    p[i] = s;
}

// Forward = R18 verbatim (best measured: 690us, 59% VALUBusy). R19's two fwd
// deltas REVERTED (distributed-E: sparse 8-lane publishes + duplicate merges
// regressed; fixed pre-gather sleep: mandatory stall lost to adaptive retry).
// Sole change vs R18: publish store issued before the vf write (both depend
// only on mv; store enters the IC queue earlier).
__global__ __launch_bounds__(512) void viterbi_fwd(
    const int* __restrict__ obs,     // [NB][NT]
    const float* __restrict__ start, // [NS]
    const float* __restrict__ trans, // [NS][NS]
    const float* __restrict__ emT,   // [NE][NS]
    float* __restrict__ vpre)        // [NB][NT][NS] exchange + bt input
{
  const int g = blockIdx.x & 63;
  const int m = blockIdx.x >> 6;       // member 0..7
  const int tid = threadIdx.x;
  const int jl = tid & 63;
  const int oct = tid >> 6;            // wave 0..7
  const int j = m * 64 + jl;           // my output column
  const int p = (m + oct) & 7;         // i-block this wave covers
  const int i0 = p * 64;

  __shared__ __align__(16) float vf[NS];
  __shared__ float part_v[2][8][64];
  __shared__ int obs_s[NT];

  obs_s[tid] = obs[g * NT + tid];
  {
    int o0 = obs[g * NT];
    vf[tid] = start[tid] + emT[(size_t)o0 * NS + tid];
    if (m == 0) vpre[(size_t)g * NT * NS + tid] = start[tid];
  }
  __syncthreads();

  for (int t = 1; t < NT; ++t) {
    const int par = t & 1;
    float e_own = 0.f;
    if (oct == 0) e_own = emT[(size_t)obs_s[t] * NS + j];  // for vf only

    // ---- per-wave gather of exactly my slice (adaptive sentinel retry) ----
    if (t >= 2 && oct != 0) {
      float e_gat = emT[(size_t)obs_s[t - 1] * NS + i0 + jl];  // in flight early
      const float* ap = vpre + ((size_t)g * NT + (t - 1)) * NS + i0 + jl;
      float ga = __hip_atomic_load(ap, __ATOMIC_RELAXED, __HIP_MEMORY_SCOPE_AGENT);
      while (__any(__float_as_uint(ga) == SENT)) {
        __builtin_amdgcn_s_sleep(1);
        ga = __hip_atomic_load(ap, __ATOMIC_RELAXED, __HIP_MEMORY_SCOPE_AGENT);
      }
      vf[i0 + jl] = ga + e_gat;  // consumed only by this wave
    }

    // ---- compute block p for column j: max only (1.5 VALU/score) ----
    float acc = -INFINITY;
    {
      const float* tp = trans + (size_t)i0 * NS + j;
      const float4* va = reinterpret_cast<const float4*>(vf + i0);
#pragma unroll
      for (int c = 0; c < 16; ++c) {
        float4 x = va[c];
        float s0 = x.x + tp[(size_t)(4 * c + 0) * NS];
        float s1 = x.y + tp[(size_t)(4 * c + 1) * NS];
        float s2 = x.z + tp[(size_t)(4 * c + 2) * NS];
        float s3 = x.w + tp[(size_t)(4 * c + 3) * NS];
        acc = fmaxf(acc, fmaxf(fmaxf(s0, s1), fmaxf(s2, s3)));
      }
    }
    if (oct != 0) part_v[par][oct][jl] = acc;
    __syncthreads();  // the ONE barrier: parts(t) ready for E(t)

    // ---- E: wave0 merges 8 partials (max), publishes vpre[t] ----
    if (oct == 0) {
      float mv = acc;
#pragma unroll
      for (int o = 1; o < 8; ++o) mv = fmaxf(mv, part_v[par][o][jl]);
      __hip_atomic_store(vpre + ((size_t)g * NT + t) * NS + j, mv,
                         __ATOMIC_RELAXED, __HIP_MEMORY_SCOPE_AGENT);
      vf[j] = mv + e_own;  // sole vf writer; read by wave0 next iter
    }
  }
}

// Backtrace, producer/consumer (R18) + R19's kept delta: mstar ships via a
// second __shfl from the matching lane's registers (it already holds
// vpre[t-1][i]), removing the dependent broadcast ds_read from the chain.
__global__ __launch_bounds__(512) void viterbi_bt(
    const int* __restrict__ obs,      // [NB][NT]
    const float* __restrict__ emT,    // [NE][NS]
    const float* __restrict__ transT, // [NS][NS], transT[j][i] = trans[i][j]
    const float* __restrict__ vpre,   // [NB][NT][NS]
    int* __restrict__ path)           // [NB][NT] int32
{
  const int b = blockIdx.x;
  const int tid = threadIdx.x;
  const int lane = tid & 63;
  const int oct = tid >> 6;

  __shared__ float vstage[2][32][NS];  // 128 KB, chunk k lives in buf k&1
  __shared__ int obs_s[NT];

  obs_s[tid] = obs[b * NT + tid];

  // stage chunk 15 (rows 480..511) into buf 1 — all 512 threads
  {
    const float4* src = reinterpret_cast<const float4*>(vpre + ((size_t)b * NT + 480) * NS);
    float4* dst = reinterpret_cast<float4*>(&vstage[1][0][0]);
    for (int i = tid; i < 32 * NS / 4; i += 512) dst[i] = src[i];
  }
  __syncthreads();

  int state = 0;
  float mstar = 0.f;
  float4 ep0, ep1;  // emission row t-1, wave0 only

  if (oct == 0) {
    // final argmax over v[511] = vstage[1][31] + e[511] (first-wins)
    const float4* vr = reinterpret_cast<const float4*>(&vstage[1][31][0]);
    const float4* er = reinterpret_cast<const float4*>(emT + (size_t)obs_s[NT - 1] * NS);
    float4 a0 = vr[2 * lane], a1 = vr[2 * lane + 1];
    float4 e0 = er[2 * lane], e1 = er[2 * lane + 1];
    float s0 = a0.x + e0.x, s1 = a0.y + e0.y, s2 = a0.z + e0.z, s3 = a0.w + e0.w;
    float s4 = a1.x + e1.x, s5 = a1.y + e1.y, s6 = a1.z + e1.z, s7 = a1.w + e1.w;
    float lm = fmaxf(fmaxf(fmaxf(s0, s1), fmaxf(s2, s3)),
                     fmaxf(fmaxf(s4, s5), fmaxf(s6, s7)));
    float M = lm;
#pragma unroll
    for (int off = 1; off < 64; off <<= 1) M = fmaxf(M, __shfl_xor(M, off));
    int k = 7;
    float sv = a1.w;
    if (s6 == M) { k = 6; sv = a1.z; }
    if (s5 == M) { k = 5; sv = a1.y; }
    if (s4 == M) { k = 4; sv = a1.x; }
    if (s3 == M) { k = 3; sv = a0.w; }
    if (s2 == M) { k = 2; sv = a0.z; }
    if (s1 == M) { k = 1; sv = a0.y; }
    if (s0 == M) { k = 0; sv = a0.x; }
    unsigned long long bal = __ballot(lm == M);
    int fl_ = __ffsll(bal) - 1;
    state = __shfl(8 * lane + k, fl_);
    mstar = __shfl(sv, fl_);  // = vpre[511][state]
    if (lane == 0) path[b * NT + (NT - 1)] = state;
    const float4* ep = reinterpret_cast<const float4*>(emT + (size_t)obs_s[NT - 2] * NS);
    ep0 = ep[2 * lane];
    ep1 = ep[2 * lane + 1];
  }

  for (int k = 15; k >= 0; --k) {
    if (oct != 0) {
      if (k > 0) {  // stage chunk k-1 into buf (k-1)&1
        const float4* src =
            reinterpret_cast<const float4*>(vpre + ((size_t)b * NT + (k - 1) * 32) * NS);
        float4* dst = reinterpret_cast<float4*>(&vstage[(k - 1) & 1][0][0]);
        for (int i = tid - 64; i < 32 * NS / 4; i += 448) dst[i] = src[i];
      }
      if (k == 15) {  // warm my transT slice (1/8 of 1MB) into this XCD's L2
        const uint4* w = reinterpret_cast<const uint4*>(transT) +
                         (size_t)((b >> 3) & 7) * (NS * NS / 4 / 8);
        for (int i = tid - 64; i < NS * NS / 4 / 8; i += 448) {
          uint4 x = w[i];
          asm volatile("" ::"v"(x.x), "v"(x.y), "v"(x.z), "v"(x.w));
        }
      }
    } else {
      const int hi = (k == 15) ? (NT - 1) : (32 * k + 32);
      const int lo = 32 * k + 1;
      const int buf = k & 1;
      for (int t = hi; t >= lo; --t) {
        // candidates row t-1 (LDS, state-independent) + emission regs
        const float4* cv = reinterpret_cast<const float4*>(&vstage[buf][(t - 1) & 31][0]);
        float4 vp0 = cv[2 * lane], vp1 = cv[2 * lane + 1];
        // dependent load: transT row for current state (L2-warm)
        const float4* tr = reinterpret_cast<const float4*>(transT + (size_t)state * NS);
        float4 t0 = tr[2 * lane], t1 = tr[2 * lane + 1];
        // prefetch next emission row (t-2), independent of state
        float4 ne0 = ep0, ne1 = ep1;
        if (t >= 2) {
          const float4* ep = reinterpret_cast<const float4*>(emT + (size_t)obs_s[t - 2] * NS);
          ne0 = ep[2 * lane];
          ne1 = ep[2 * lane + 1];
        }
        float c0 = vp0.x + ep0.x, c1 = vp0.y + ep0.y, c2 = vp0.z + ep0.z, c3 = vp0.w + ep0.w;
        float c4 = vp1.x + ep1.x, c5 = vp1.y + ep1.y, c6 = vp1.z + ep1.z, c7 = vp1.w + ep1.w;
        bool m0 = (c0 + t0.x) == mstar, m1 = (c1 + t0.y) == mstar;
        bool m2 = (c2 + t0.z) == mstar, m3 = (c3 + t0.w) == mstar;
        bool m4 = (c4 + t1.x) == mstar, m5 = (c5 + t1.y) == mstar;
        bool m6 = (c6 + t1.z) == mstar, m7 = (c7 + t1.w) == mstar;
        int kk = 7;
        float sv = vp1.w;
        if (m6) { kk = 6; sv = vp1.z; }
        if (m5) { kk = 5; sv = vp1.y; }
        if (m4) { kk = 4; sv = vp1.x; }
        if (m3) { kk = 3; sv = vp0.w; }
        if (m2) { kk = 2; sv = vp0.z; }
        if (m1) { kk = 1; sv = vp0.y; }
        if (m0) { kk = 0; sv = vp0.x; }
        unsigned long long bal = __ballot(m0 | m1 | m2 | m3 | m4 | m5 | m6 | m7);
        int fl_ = __ffsll(bal) - 1;
        state = __shfl(8 * lane + kk, fl_);
        mstar = __shfl(sv, fl_);  // = vpre[t-1][state], from matching lane's regs
        if (lane == 0) path[b * NT + t - 1] = state;
        ep0 = ne0;
        ep1 = ne1;
      }
    }
    __syncthreads();  // chunk k-1 staged; wave0 done with chunk k
  }
}

extern "C" void kernel_launch(void* const* d_in, const int* in_sizes, int n_in,
                              void* d_out, int out_size, void* d_ws, size_t ws_size,
                              hipStream_t stream) {
  const int* obs = (const int*)d_in[0];       // [64][512]
  const float* start = (const float*)d_in[1]; // [512]
  const float* trans = (const float*)d_in[2]; // [512][512]
  const float* emis = (const float*)d_in[3];  // [512][2048]
  int* path = (int*)d_out;                    // [64][512] int32

  char* ws = (char*)d_ws;
  float* emT = (float*)ws;                           // [2048][512] = 4 MB
  float* transT = (float*)(ws + (4ull << 20));       // [512][512]  = 1 MB
  float* vpre = (float*)(ws + (5ull << 20));         // [64][512][512] = 64 MB

  fill_sentinel<<<1024, 256, 0, stream>>>(vpre);

  dim3 tb(32, 8);
  transpose_k<<<dim3(NE / 32, NS / 32), tb, 0, stream>>>(emis, emT, NS, NE);
  transpose_k<<<dim3(NS / 32, NS / 32), tb, 0, stream>>>(trans, transT, NS, NS);
  viterbi_fwd<<<512, 512, 0, stream>>>(obs, start, trans, emT, vpre);
  viterbi_bt<<<NB, 512, 0, stream>>>(obs, emT, transT, vpre, path);
}

// Round 21
// 898.477 us; speedup vs baseline: 1.0848x; 1.0035x over previous
//
#include <hip/hip_runtime.h>
#include <math.h>

#define NS 512
#define NE 2048
#define NB 64
#define NT 512
#define SENT 0x7FC0DEADu  // NaN payload; real values are always finite

// Fused prep: [0,1024) transpose emis->emT, [1024,1280) transpose trans->transT,
// [1280,2304) sentinel-fill vpre. One dispatch instead of three (launch-gap +
// serialization savings; the three regions are independent writes).
__global__ __launch_bounds__(256) void prep(const float* __restrict__ emis,
                                            const float* __restrict__ trans,
                                            float* __restrict__ emT,
                                            float* __restrict__ transT,
                                            float* __restrict__ vpre) {
  __shared__ float tile[32][33];
  const int bid = blockIdx.x;
  const int tx = threadIdx.x & 31;
  const int ty = threadIdx.x >> 5;  // 0..7

  if (bid < 1024) {
    // emis [NS][NE] -> emT [NE][NS]; grid (NE/32=64) x (NS/32=16)
    int bx = bid & 63, by = bid >> 6;
    int c0 = bx * 32, r0 = by * 32;
#pragma unroll
    for (int k = 0; k < 32; k += 8)
      tile[ty + k][tx] = emis[(size_t)(r0 + ty + k) * NE + (c0 + tx)];
    __syncthreads();
#pragma unroll
    for (int k = 0; k < 32; k += 8)
      emT[(size_t)(c0 + ty + k) * NS + (r0 + tx)] = tile[tx][ty + k];
  } else if (bid < 1280) {
    // trans [NS][NS] -> transT [NS][NS]; grid 16 x 16
    int r = bid - 1024;
    int bx = r & 15, by = r >> 4;
    int c0 = bx * 32, r0 = by * 32;
#pragma unroll
    for (int k = 0; k < 32; k += 8)
      tile[ty + k][tx] = trans[(size_t)(r0 + ty + k) * NS + (c0 + tx)];
    __syncthreads();
#pragma unroll
    for (int k = 0; k < 32; k += 8)
      transT[(size_t)(c0 + ty + k) * NS + (r0 + tx)] = tile[tx][ty + k];
  } else {
    // sentinel-fill vpre (64 MB), 1024 blocks, uint4 grid-stride
    uint4 s = make_uint4(SENT, SENT, SENT, SENT);
    uint4* p = reinterpret_cast<uint4*>(vpre);
    const size_t n4 = (size_t)NB * NT * NS / 4;
    for (size_t i = (size_t)(bid - 1280) * 256 + threadIdx.x; i < n4; i += 1024 * 256)
      p[i] = s;
  }
}

// Forward = R20 (best measured: 686us, 59.9% VALUBusy). Dataflow column-slice,
// max-only, sentinel exchange. Grid 512 = 64 groups x 8 members; member m owns
// columns [64m,64m+64); wave oct owns i-block (m+oct)&7 and gathers exactly
// the slice it consumes (adaptive sentinel retry); single barrier per iter;
// wave0 merges+publishes. 511 sequential IC round-trips = the latency floor.
__global__ __launch_bounds__(512) void viterbi_fwd(
    const int* __restrict__ obs,     // [NB][NT]
    const float* __restrict__ start, // [NS]
    const float* __restrict__ trans, // [NS][NS]
    const float* __restrict__ emT,   // [NE][NS]
    float* __restrict__ vpre)        // [NB][NT][NS] exchange + bt input
{
  const int g = blockIdx.x & 63;
  const int m = blockIdx.x >> 6;       // member 0..7
  const int tid = threadIdx.x;
  const int jl = tid & 63;
  const int oct = tid >> 6;            // wave 0..7
  const int j = m * 64 + jl;           // my output column
  const int p = (m + oct) & 7;         // i-block this wave covers
  const int i0 = p * 64;

  __shared__ __align__(16) float vf[NS];
  __shared__ float part_v[2][8][64];
  __shared__ int obs_s[NT];

  obs_s[tid] = obs[g * NT + tid];
  {
    int o0 = obs[g * NT];
    vf[tid] = start[tid] + emT[(size_t)o0 * NS + tid];
    if (m == 0) vpre[(size_t)g * NT * NS + tid] = start[tid];
  }
  __syncthreads();

  for (int t = 1; t < NT; ++t) {
    const int par = t & 1;
    float e_own = 0.f;
    if (oct == 0) e_own = emT[(size_t)obs_s[t] * NS + j];  // for vf only

    // ---- per-wave gather of exactly my slice (adaptive sentinel retry) ----
    if (t >= 2 && oct != 0) {
      float e_gat = emT[(size_t)obs_s[t - 1] * NS + i0 + jl];  // in flight early
      const float* ap = vpre + ((size_t)g * NT + (t - 1)) * NS + i0 + jl;
      float ga = __hip_atomic_load(ap, __ATOMIC_RELAXED, __HIP_MEMORY_SCOPE_AGENT);
      while (__any(__float_as_uint(ga) == SENT)) {
        __builtin_amdgcn_s_sleep(1);
        ga = __hip_atomic_load(ap, __ATOMIC_RELAXED, __HIP_MEMORY_SCOPE_AGENT);
      }
      vf[i0 + jl] = ga + e_gat;  // consumed only by this wave
    }

    // ---- compute block p for column j: max only (1.5 VALU/score) ----
    float acc = -INFINITY;
    {
      const float* tp = trans + (size_t)i0 * NS + j;
      const float4* va = reinterpret_cast<const float4*>(vf + i0);
#pragma unroll
      for (int c = 0; c < 16; ++c) {
        float4 x = va[c];
        float s0 = x.x + tp[(size_t)(4 * c + 0) * NS];
        float s1 = x.y + tp[(size_t)(4 * c + 1) * NS];
        float s2 = x.z + tp[(size_t)(4 * c + 2) * NS];
        float s3 = x.w + tp[(size_t)(4 * c + 3) * NS];
        acc = fmaxf(acc, fmaxf(fmaxf(s0, s1), fmaxf(s2, s3)));
      }
    }
    if (oct != 0) part_v[par][oct][jl] = acc;
    __syncthreads();  // the ONE barrier: parts(t) ready for E(t)

    // ---- E: wave0 merges 8 partials (max), publishes vpre[t] ----
    if (oct == 0) {
      float mv = acc;
#pragma unroll
      for (int o = 1; o < 8; ++o) mv = fmaxf(mv, part_v[par][o][jl]);
      __hip_atomic_store(vpre + ((size_t)g * NT + t) * NS + j, mv,
                         __ATOMIC_RELAXED, __HIP_MEMORY_SCOPE_AGENT);
      vf[j] = mv + e_own;  // sole vf writer; read by wave0 next iter
    }
  }
}

// Backtrace, producer/consumer: wave0 chases via exact value-match (bit-
// identical recomputation of fwd's expressions -> first-wins argmax); waves
// 1-7 stage vpre chunks into double-buffered LDS ahead and warm transT into
// L2 (slice-partitioned; 8 blocks/XCD jointly cover all of transT). mstar
// ships via a second __shfl from the matching lane's registers.
__global__ __launch_bounds__(512) void viterbi_bt(
    const int* __restrict__ obs,      // [NB][NT]
    const float* __restrict__ emT,    // [NE][NS]
    const float* __restrict__ transT, // [NS][NS], transT[j][i] = trans[i][j]
    const float* __restrict__ vpre,   // [NB][NT][NS]
    int* __restrict__ path)           // [NB][NT] int32
{
  const int b = blockIdx.x;
  const int tid = threadIdx.x;
  const int lane = tid & 63;
  const int oct = tid >> 6;

  __shared__ float vstage[2][32][NS];  // 128 KB, chunk k lives in buf k&1
  __shared__ int obs_s[NT];

  obs_s[tid] = obs[b * NT + tid];

  // stage chunk 15 (rows 480..511) into buf 1 — all 512 threads
  {
    const float4* src = reinterpret_cast<const float4*>(vpre + ((size_t)b * NT + 480) * NS);
    float4* dst = reinterpret_cast<float4*>(&vstage[1][0][0]);
    for (int i = tid; i < 32 * NS / 4; i += 512) dst[i] = src[i];
  }
  __syncthreads();

  int state = 0;
  float mstar = 0.f;
  float4 ep0, ep1;  // emission row t-1, wave0 only

  if (oct == 0) {
    // final argmax over v[511] = vstage[1][31] + e[511] (first-wins)
    const float4* vr = reinterpret_cast<const float4*>(&vstage[1][31][0]);
    const float4* er = reinterpret_cast<const float4*>(emT + (size_t)obs_s[NT - 1] * NS);
    float4 a0 = vr[2 * lane], a1 = vr[2 * lane + 1];
    float4 e0 = er[2 * lane], e1 = er[2 * lane + 1];
    float s0 = a0.x + e0.x, s1 = a0.y + e0.y, s2 = a0.z + e0.z, s3 = a0.w + e0.w;
    float s4 = a1.x + e1.x, s5 = a1.y + e1.y, s6 = a1.z + e1.z, s7 = a1.w + e1.w;
    float lm = fmaxf(fmaxf(fmaxf(s0, s1), fmaxf(s2, s3)),
                     fmaxf(fmaxf(s4, s5), fmaxf(s6, s7)));
    float M = lm;
#pragma unroll
    for (int off = 1; off < 64; off <<= 1) M = fmaxf(M, __shfl_xor(M, off));
    int k = 7;
    float sv = a1.w;
    if (s6 == M) { k = 6; sv = a1.z; }
    if (s5 == M) { k = 5; sv = a1.y; }
    if (s4 == M) { k = 4; sv = a1.x; }
    if (s3 == M) { k = 3; sv = a0.w; }
    if (s2 == M) { k = 2; sv = a0.z; }
    if (s1 == M) { k = 1; sv = a0.y; }
    if (s0 == M) { k = 0; sv = a0.x; }
    unsigned long long bal = __ballot(lm == M);
    int fl_ = __ffsll(bal) - 1;
    state = __shfl(8 * lane + k, fl_);
    mstar = __shfl(sv, fl_);  // = vpre[511][state]
    if (lane == 0) path[b * NT + (NT - 1)] = state;
    const float4* ep = reinterpret_cast<const float4*>(emT + (size_t)obs_s[NT - 2] * NS);
    ep0 = ep[2 * lane];
    ep1 = ep[2 * lane + 1];
  }

  for (int k = 15; k >= 0; --k) {
    if (oct != 0) {
      if (k > 0) {  // stage chunk k-1 into buf (k-1)&1
        const float4* src =
            reinterpret_cast<const float4*>(vpre + ((size_t)b * NT + (k - 1) * 32) * NS);
        float4* dst = reinterpret_cast<float4*>(&vstage[(k - 1) & 1][0][0]);
        for (int i = tid - 64; i < 32 * NS / 4; i += 448) dst[i] = src[i];
      }
      if (k == 15) {  // warm my transT slice (1/8 of 1MB) into this XCD's L2
        const uint4* w = reinterpret_cast<const uint4*>(transT) +
                         (size_t)((b >> 3) & 7) * (NS * NS / 4 / 8);
        for (int i = tid - 64; i < NS * NS / 4 / 8; i += 448) {
          uint4 x = w[i];
          asm volatile("" ::"v"(x.x), "v"(x.y), "v"(x.z), "v"(x.w));
        }
      }
    } else {
      const int hi = (k == 15) ? (NT - 1) : (32 * k + 32);
      const int lo = 32 * k + 1;
      const int buf = k & 1;
      for (int t = hi; t >= lo; --t) {
        // candidates row t-1 (LDS, state-independent) + emission regs
        const float4* cv = reinterpret_cast<const float4*>(&vstage[buf][(t - 1) & 31][0]);
        float4 vp0 = cv[2 * lane], vp1 = cv[2 * lane + 1];
        // dependent load: transT row for current state (L2-warm)
        const float4* tr = reinterpret_cast<const float4*>(transT + (size_t)state * NS);
        float4 t0 = tr[2 * lane], t1 = tr[2 * lane + 1];
        // prefetch next emission row (t-2), independent of state
        float4 ne0 = ep0, ne1 = ep1;
        if (t >= 2) {
          const float4* ep = reinterpret_cast<const float4*>(emT + (size_t)obs_s[t - 2] * NS);
          ne0 = ep[2 * lane];
          ne1 = ep[2 * lane + 1];
        }
        float c0 = vp0.x + ep0.x, c1 = vp0.y + ep0.y, c2 = vp0.z + ep0.z, c3 = vp0.w + ep0.w;
        float c4 = vp1.x + ep1.x, c5 = vp1.y + ep1.y, c6 = vp1.z + ep1.z, c7 = vp1.w + ep1.w;
        bool m0 = (c0 + t0.x) == mstar, m1 = (c1 + t0.y) == mstar;
        bool m2 = (c2 + t0.z) == mstar, m3 = (c3 + t0.w) == mstar;
        bool m4 = (c4 + t1.x) == mstar, m5 = (c5 + t1.y) == mstar;
        bool m6 = (c6 + t1.z) == mstar, m7 = (c7 + t1.w) == mstar;
        int kk = 7;
        float sv = vp1.w;
        if (m6) { kk = 6; sv = vp1.z; }
        if (m5) { kk = 5; sv = vp1.y; }
        if (m4) { kk = 4; sv = vp1.x; }
        if (m3) { kk = 3; sv = vp0.w; }
        if (m2) { kk = 2; sv = vp0.z; }
        if (m1) { kk = 1; sv = vp0.y; }
        if (m0) { kk = 0; sv = vp0.x; }
        unsigned long long bal = __ballot(m0 | m1 | m2 | m3 | m4 | m5 | m6 | m7);
        int fl_ = __ffsll(bal) - 1;
        state = __shfl(8 * lane + kk, fl_);
        mstar = __shfl(sv, fl_);  // = vpre[t-1][state], from matching lane's regs
        if (lane == 0) path[b * NT + t - 1] = state;
        ep0 = ne0;
        ep1 = ne1;
      }
    }
    __syncthreads();  // chunk k-1 staged; wave0 done with chunk k
  }
}

extern "C" void kernel_launch(void* const* d_in, const int* in_sizes, int n_in,
                              void* d_out, int out_size, void* d_ws, size_t ws_size,
                              hipStream_t stream) {
  const int* obs = (const int*)d_in[0];       // [64][512]
  const float* start = (const float*)d_in[1]; // [512]
  const float* trans = (const float*)d_in[2]; // [512][512]
  const float* emis = (const float*)d_in[3];  // [512][2048]
  int* path = (int*)d_out;                    // [64][512] int32

  char* ws = (char*)d_ws;
  float* emT = (float*)ws;                           // [2048][512] = 4 MB
  float* transT = (float*)(ws + (4ull << 20));       // [512][512]  = 1 MB
  float* vpre = (float*)(ws + (5ull << 20));         // [64][512][512] = 64 MB

  prep<<<2304, 256, 0, stream>>>(emis, trans, emT, transT, vpre);
  viterbi_fwd<<<512, 512, 0, stream>>>(obs, start, trans, emT, vpre);
  viterbi_bt<<<NB, 512, 0, stream>>>(obs, emT, transT, vpre, path);
}